// Round 7
// baseline (244.455 us; speedup 1.0000x reference)
//
#include <hip/hip_runtime.h>
#include <math.h>
#include <float.h>

#define PSZ 256
#define NPATCH 127
#define L 16129            // 127*127
#define KTOP 4
#define TMAIN 256
#define RPT 2              // rows per thread
#define ROWS_PER_BLOCK (TMAIN * RPT)   // 512
#define NROWBLK 32                     // 32*512 = 16384 >= L
#define NS 32
#define SEGLEN 505                     // ceil(L/32); 32*505 = 16160 >= 16129
#define MSTRIDE 508                    // float4-aligned LDS stride
#define ROWPAD 16384
#define GRP 8                          // tournament group size (m's per group)

typedef float f2 __attribute__((ext_vector_type(2)));

// ---- workspace layout (float elements) ----
static constexpr size_t OFF_CMAX = 0;                          // [2][256][256]
static constexpr size_t OFF_CMIN = OFF_CMAX + 2 * PSZ * PSZ;
static constexpr size_t OFF_REFG = OFF_CMIN + 2 * PSZ * PSZ;
static constexpr size_t OFF_XG   = OFF_REFG + 2 * PSZ * PSZ;
static constexpr size_t OFF_MUI  = OFF_XG   + 2 * PSZ * PSZ;   // [18]
static constexpr size_t OFF_MUR  = OFF_MUI  + 20;
static constexpr size_t OFF_A    = OFF_MUR  + 20;              // [2][L][9] input_norm
static constexpr size_t OFF_B    = OFF_A    + 290324;          // [2][9][L] ref_norm (p-major)
static constexpr size_t OFF_BT   = OFF_B    + 290324;          // [2][L][9] ref_norm (m-major)
static constexpr size_t OFF_IDX  = OFF_BT   + 290324;          // [2][L][4] final idx (int)
static constexpr size_t OFF_G4   = OFF_IDX  + 2 * L * 4;       // [2][L][4] winning group bases (int)
static constexpr size_t OFF_PV   = OFF_G4   + 2 * L * 4;       // [2][NS][ROWPAD][4] group-max vals
static constexpr size_t OFF_PI   = OFF_PV   + (size_t)2 * NS * ROWPAD * 4;  // group bases (int)
// end = OFF_PI + 8.39M ~= 10.04M floats (40.2 MB) <= 41.07 MB proven present
// (round 2 ran its 41.07 MB NS=32 layout successfully).

// insert (rm, gb) into sorted-desc (g0..g3, i0..i3); strict > keeps the
// earlier entry on value ties -- candidates arrive in ascending gb.
__device__ __forceinline__ void insg(float rm, int gb,
    float& g0, float& g1, float& g2, float& g3,
    int& i0, int& i1, int& i2, int& i3) {
  bool c0 = rm > g0, c1 = rm > g1, c2 = rm > g2, c3 = rm > g3;
  g3 = c2 ? g2 : (c3 ? rm : g3);  i3 = c2 ? i2 : (c3 ? gb : i3);
  g2 = c1 ? g1 : (c2 ? rm : g2);  i2 = c1 ? i1 : (c2 ? gb : i2);
  g1 = c0 ? g0 : (c1 ? rm : g1);  i1 = c0 ? i0 : (c1 ? gb : i1);
  g0 = c0 ? rm : g0;              i0 = c0 ? gb : i0;
}

// composite-order insert: (v desc, m asc). Order-independent and
// duplicate-safe (identical (v,m) re-inserted is a no-op).
__device__ __forceinline__ void ins4c(float v, int m,
    float& v0, float& v1, float& v2, float& v3,
    int& x0, int& x1, int& x2, int& x3) {
  bool c0 = (v > v0) || (v == v0 && m < x0);
  bool c1 = (v > v1) || (v == v1 && m < x1);
  bool c2 = (v > v2) || (v == v2 && m < x2);
  bool c3 = (v > v3) || (v == v3 && m < x3);
  v3 = c2 ? v2 : (c3 ? v : v3);  x3 = c2 ? x2 : (c3 ? m : x3);
  v2 = c1 ? v1 : (c2 ? v : v2);  x2 = c1 ? x1 : (c2 ? m : x2);
  v1 = c0 ? v0 : (c1 ? v : v1);  x1 = c0 ? x0 : (c1 ? m : x1);
  v0 = c0 ? v : v0;              x0 = c0 ? m : x0;
}

// k1: per pixel: channel max/min of x, channel mean of ref, copy x -> out[:, :3]
__global__ void k1_pixel(const float* __restrict__ x, const float* __restrict__ ref,
                         float* __restrict__ ws, float* __restrict__ out) {
  int id = blockIdx.x * 256 + threadIdx.x;
  if (id >= 2 * PSZ * PSZ) return;
  int b = id >> 16;
  int pix = id & 0xFFFF;
  const float* xb = x + (size_t)b * 3 * PSZ * PSZ + pix;
  float c0 = xb[0], c1 = xb[PSZ * PSZ], c2 = xb[2 * PSZ * PSZ];
  ws[OFF_CMAX + id] = fmaxf(fmaxf(c0, c1), c2);
  ws[OFF_CMIN + id] = fminf(fminf(c0, c1), c2);
  const float* rb = ref + (size_t)b * 3 * PSZ * PSZ + pix;
  ws[OFF_REFG + id] = (rb[0] + rb[PSZ * PSZ] + rb[2 * PSZ * PSZ]) / 3.0f;
  float* ob = out + (size_t)b * 7 * PSZ * PSZ + pix;
  ob[0] = c0; ob[PSZ * PSZ] = c1; ob[2 * PSZ * PSZ] = c2;
}

// k2: x_gray = 3x3 clipped-window max of cmax - cmin
__global__ void k2_gray(float* __restrict__ ws) {
  int id = blockIdx.x * 256 + threadIdx.x;
  if (id >= 2 * PSZ * PSZ) return;
  int b = id >> 16;
  int pix = id & 0xFFFF;
  int y = pix >> 8, xx = pix & 255;
  const float* cm = ws + OFF_CMAX + ((size_t)b << 16);
  float m = -3.402823466e+38f;
  for (int dy = -1; dy <= 1; ++dy) {
    int yy = y + dy;
    if (yy < 0 || yy > 255) continue;
    for (int dx = -1; dx <= 1; ++dx) {
      int xc = xx + dx;
      if (xc < 0 || xc > 255) continue;
      m = fmaxf(m, cm[yy * PSZ + xc]);
    }
  }
  ws[OFF_XG + id] = m - ws[OFF_CMIN + id];
}

// k4: per-(b,p) mean over L in f64 (deterministic tree reduction)
__global__ void k4_mean(float* __restrict__ ws) {
  __shared__ double sm[256];
  int which = blockIdx.x / 18;  // 0 = input(xg), 1 = ref(rg)
  int bp = blockIdx.x % 18;
  int b = bp / 9, p = bp % 9;
  int di = p / 3, dj = p % 3;
  const float* g = ws + (which ? OFF_REFG : OFF_XG) + ((size_t)b << 16);
  double s = 0.0;
  for (int l = threadIdx.x; l < L; l += 256) {
    int i = l / NPATCH, j = l % NPATCH;
    s += (double)g[(2 * i + di) * PSZ + 2 * j + dj];
  }
  sm[threadIdx.x] = s;
  __syncthreads();
  for (int st = 128; st > 0; st >>= 1) {
    if ((int)threadIdx.x < st) sm[threadIdx.x] += sm[threadIdx.x + st];
    __syncthreads();
  }
  if (threadIdx.x == 0)
    ws[(which ? OFF_MUR : OFF_MUI) + bp] = (float)(sm[0] / (double)L);
}

// k5: per l compute patch values + uncentered norms, then
// A[b][l][9] = (ip - muI)/nI ; B[b][9][L] and BT[b][l][9] = (rp - muR)/nR
__global__ void k5_norm(float* __restrict__ ws) {
  int id = blockIdx.x * 256 + threadIdx.x;
  if (id >= 2 * L) return;
  int b = id / L, l = id % L;
  int i = l / NPATCH, j = l % NPATCH;
  const float* xg = ws + OFF_XG + ((size_t)b << 16);
  const float* rg = ws + OFF_REFG + ((size_t)b << 16);
  float vi[9], vr[9];
  float si = 0.f, sr = 0.f;
#pragma unroll
  for (int p = 0; p < 9; ++p) {
    int di = p / 3, dj = p % 3;
    vi[p] = xg[(2 * i + di) * PSZ + 2 * j + dj];
    vr[p] = rg[(2 * i + di) * PSZ + 2 * j + dj];
    si += vi[p] * vi[p];
    sr += vr[p] * vr[p];
  }
  float ni = sqrtf(si), nr = sqrtf(sr);
#pragma unroll
  for (int p = 0; p < 9; ++p) {
    float mi = ws[OFF_MUI + b * 9 + p];
    float mr = ws[OFF_MUR + b * 9 + p];
    float bn = (vr[p] - mr) / nr;
    ws[OFF_A + ((size_t)b * L + l) * 9 + p] = (vi[p] - mi) / ni;
    ws[OFF_B + ((size_t)b * 9 + p) * L + l] = bn;
    ws[OFF_BT + ((size_t)b * L + l) * 9 + p] = bn;
  }
}

// k6: fused ncc + per-(row,segment) top-4 GROUP-MAX tournament (groups of 8 m).
// Superset property: the row's top-4 elements lie in the top-4 groups by
// (group-max desc, base asc) -- exact recovery happens in k7a/k7b.
// grid: 2(b) x 32(rowblk) x 32(seg) = 2048 blocks (8/CU), 256 threads,
// 2 rows/thread, 8 m/iter. Round 6 at NS=16 was 1/3 stall-bound (VALUBusy
// 66%, occupancy 33%, LDS-limited to 4 blocks/CU); halving the segment
// doubles residency to 8 blocks/CU (32 waves/CU) to hide DS latency.
__global__ __launch_bounds__(TMAIN, 2) void k6_topk(float* __restrict__ ws) {
  __shared__ float lds[9 * MSTRIDE];  // 18288 B -> 8 blocks/CU

  int bid = blockIdx.x;
  int seg = bid % NS;
  int rowblk = (bid / NS) % NROWBLK;
  int b = bid / (NS * NROWBLK);
  int m0 = seg * SEGLEN;
  int mend = m0 + SEGLEN;
  if (mend > L) mend = L;
  int mlen = mend - m0;

  const float* Bg = ws + OFF_B + (size_t)b * 9 * L + m0;
  for (int p = 0; p < 9; ++p)
    for (int mm = threadIdx.x; mm < mlen; mm += TMAIN)
      lds[p * MSTRIDE + mm] = Bg[(size_t)p * L + mm];
  __syncthreads();

  int row0 = rowblk * ROWS_PER_BLOCK + threadIdx.x * RPT;
  int r0 = row0 < L - 1 ? row0 : L - 1;
  int r1 = row0 + 1 < L - 1 ? row0 + 1 : L - 1;
  float a0[9], a1[9];
  {
    const float* Ap0 = ws + OFF_A + ((size_t)b * L + r0) * 9;
    const float* Ap1 = ws + OFF_A + ((size_t)b * L + r1) * 9;
#pragma unroll
    for (int p = 0; p < 9; ++p) { a0[p] = Ap0[p]; a1[p] = Ap1[p]; }
  }

  float g00 = -FLT_MAX, g01 = g00, g02 = g00, g03 = g00;
  float g10 = g00, g11 = g00, g12 = g00, g13 = g00;
  int i00 = 0, i01 = 0, i02 = 0, i03 = 0;
  int i10 = 0, i11 = 0, i12 = 0, i13 = 0;

  int ngrp = mlen >> 3;  // full groups of 8
  for (int g = 0; g < ngrp; ++g) {
    int mm = g << 3;
    f2 s0a, s0b, s0c, s0d, s1a, s1b, s1c, s1d;
#pragma unroll
    for (int p = 0; p < 9; ++p) {
      const float* base = &lds[p * MSTRIDE + mm];
      f2 b0 = *(const f2*)(base + 0);
      f2 b1 = *(const f2*)(base + 2);
      f2 b2 = *(const f2*)(base + 4);
      f2 b3 = *(const f2*)(base + 6);
      f2 va = {a0[p], a0[p]};
      f2 vb = {a1[p], a1[p]};
      if (p == 0) {
        s0a = va * b0; s0b = va * b1; s0c = va * b2; s0d = va * b3;
        s1a = vb * b0; s1b = vb * b1; s1c = vb * b2; s1d = vb * b3;
      } else {
        s0a = __builtin_elementwise_fma(va, b0, s0a);
        s0b = __builtin_elementwise_fma(va, b1, s0b);
        s0c = __builtin_elementwise_fma(va, b2, s0c);
        s0d = __builtin_elementwise_fma(va, b3, s0d);
        s1a = __builtin_elementwise_fma(vb, b0, s1a);
        s1b = __builtin_elementwise_fma(vb, b1, s1b);
        s1c = __builtin_elementwise_fma(vb, b2, s1c);
        s1d = __builtin_elementwise_fma(vb, b3, s1d);
      }
    }
    f2 rv0 = __builtin_elementwise_max(__builtin_elementwise_max(s0a, s0b),
                                       __builtin_elementwise_max(s0c, s0d));
    f2 rv1 = __builtin_elementwise_max(__builtin_elementwise_max(s1a, s1b),
                                       __builtin_elementwise_max(s1c, s1d));
    float rm0 = fmaxf(rv0.x, rv0.y);
    float rm1 = fmaxf(rv1.x, rv1.y);
    int gb = m0 + mm;
    insg(rm0, gb, g00, g01, g02, g03, i00, i01, i02, i03);
    insg(rm1, gb, g10, g11, g12, g13, i10, i11, i12, i13);
  }
  // tail (< 8 m): one partial group; recovery clips its scan to L.
  int tb = ngrp << 3;
  if (tb < mlen) {
    float rt0 = -FLT_MAX, rt1 = -FLT_MAX;
    for (int mm = tb; mm < mlen; ++mm) {
      float bb = lds[mm];
      float sv0 = a0[0] * bb, sv1 = a1[0] * bb;
#pragma unroll
      for (int p = 1; p < 9; ++p) {
        bb = lds[p * MSTRIDE + mm];
        sv0 = fmaf(a0[p], bb, sv0); sv1 = fmaf(a1[p], bb, sv1);
      }
      rt0 = fmaxf(rt0, sv0); rt1 = fmaxf(rt1, sv1);
    }
    insg(rt0, m0 + tb, g00, g01, g02, g03, i00, i01, i02, i03);
    insg(rt1, m0 + tb, g10, g11, g12, g13, i10, i11, i12, i13);
  }

  int* wsi = (int*)ws;
  if (row0 < L) {
    size_t base = (((size_t)b * NS + seg) * ROWPAD + row0) * 4;
    ws[OFF_PV + base + 0] = g00; ws[OFF_PV + base + 1] = g01;
    ws[OFF_PV + base + 2] = g02; ws[OFF_PV + base + 3] = g03;
    wsi[OFF_PI + base + 0] = i00; wsi[OFF_PI + base + 1] = i01;
    wsi[OFF_PI + base + 2] = i02; wsi[OFF_PI + base + 3] = i03;
  }
  if (row0 + 1 < L) {
    size_t base = (((size_t)b * NS + seg) * ROWPAD + row0 + 1) * 4;
    ws[OFF_PV + base + 0] = g10; ws[OFF_PV + base + 1] = g11;
    ws[OFF_PV + base + 2] = g12; ws[OFF_PV + base + 3] = g13;
    wsi[OFF_PI + base + 0] = i10; wsi[OFF_PI + base + 1] = i11;
    wsi[OFF_PI + base + 2] = i12; wsi[OFF_PI + base + 3] = i13;
  }
}

// k7a: per row merge 32 segs x 4 (group-max, base) -> top-4 groups by
// (max desc, base asc); store the 4 winning bases.
__global__ void k7a_groups(float* __restrict__ ws) {
  int id = blockIdx.x * 256 + threadIdx.x;
  if (id >= 2 * L) return;
  int b = id / L, row = id % L;
  float v0 = -FLT_MAX, v1 = v0, v2 = v0, v3 = v0;
  int x0 = 0x7FFFFFFF, x1 = x0, x2 = x0, x3 = x0;
  const int* wsi_c = (const int*)ws;
  for (int s = 0; s < NS; ++s) {
    size_t base = (((size_t)b * NS + s) * ROWPAD + row) * 4;
#pragma unroll
    for (int q = 0; q < 4; ++q) {
      float val = ws[OFF_PV + base + q];
      int gb = wsi_c[OFF_PI + base + q];
      ins4c(val, gb, v0, v1, v2, v3, x0, x1, x2, x3);
    }
  }
  int* wsi = (int*)ws;
  size_t gb4 = OFF_G4 + (size_t)id * 4;
  wsi[gb4] = x0; wsi[gb4 + 1] = x1; wsi[gb4 + 2] = x2; wsi[gb4 + 3] = x3;
}

// k7b: exact recovery -- rescan the 4 winning groups (<= 32 m's) with the
// identical fmaf chain, exact composite top-4 -> IDX.
__global__ void k7b_recover(float* __restrict__ ws) {
  int id = blockIdx.x * 256 + threadIdx.x;
  if (id >= 2 * L) return;
  int b = id / L, row = id % L;
  float a[9];
  const float* Ap = ws + OFF_A + ((size_t)b * L + row) * 9;
#pragma unroll
  for (int p = 0; p < 9; ++p) a[p] = Ap[p];
  const int* wsi_c = (const int*)ws;
  float v0 = -FLT_MAX, v1 = v0, v2 = v0, v3 = v0;
  int x0 = 0x7FFFFFFF, x1 = x0, x2 = x0, x3 = x0;
#pragma unroll
  for (int slot = 0; slot < 4; ++slot) {
    int gb = wsi_c[OFF_G4 + (size_t)id * 4 + slot];
    int ge = gb + GRP; if (ge > L) ge = L;
    for (int mm = gb; mm < ge; ++mm) {
      const float* bt = ws + OFF_BT + ((size_t)b * L + mm) * 9;
      float s = a[0] * bt[0];
#pragma unroll
      for (int p = 1; p < 9; ++p) s = fmaf(a[p], bt[p], s);
      ins4c(s, mm, v0, v1, v2, v3, x0, x1, x2, x3);
    }
  }
  int* wsi = (int*)ws;
  size_t ib = OFF_IDX + (size_t)id * 4;
  wsi[ib] = x0; wsi[ib + 1] = x1; wsi[ib + 2] = x2; wsi[ib + 3] = x3;
}

// k8: fold (overlap-add) via per-output-pixel gather; reads ref_gray directly
__global__ void k8_fold(const float* __restrict__ ws, float* __restrict__ out) {
  int id = blockIdx.x * 256 + threadIdx.x;
  if (id >= 2 * KTOP * PSZ * PSZ) return;
  int b = id / (KTOP * PSZ * PSZ);
  int rem = id % (KTOP * PSZ * PSZ);
  int kk = rem >> 16;
  int pix = rem & 0xFFFF;
  int y = pix >> 8, xx = pix & 255;
  const int* wsi = (const int*)ws;
  const float* rg = ws + OFF_REFG + ((size_t)b << 16);
  float acc = 0.f;
  for (int di = 0; di < 3; ++di) {
    int yy = y - di;
    if (yy < 0 || (yy & 1) || (yy >> 1) >= NPATCH) continue;
    int i = yy >> 1;
    for (int dj = 0; dj < 3; ++dj) {
      int xc = xx - dj;
      if (xc < 0 || (xc & 1) || (xc >> 1) >= NPATCH) continue;
      int j = xc >> 1;
      int l = i * NPATCH + j;
      int m = wsi[OFF_IDX + ((size_t)b * L + l) * 4 + kk];
      int mi = m / NPATCH, mj = m % NPATCH;
      acc += rg[(2 * mi + di) * PSZ + 2 * mj + dj];
    }
  }
  out[(((size_t)b * 7 + 3 + kk) * PSZ + y) * PSZ + xx] = acc;
}

extern "C" void kernel_launch(void* const* d_in, const int* in_sizes, int n_in,
                              void* d_out, int out_size, void* d_ws, size_t ws_size,
                              hipStream_t stream) {
  const float* x = (const float*)d_in[0];
  const float* ref = (const float*)d_in[1];
  float* ws = (float*)d_ws;
  float* out = (float*)d_out;

  k1_pixel<<<512, 256, 0, stream>>>(x, ref, ws, out);
  k2_gray<<<512, 256, 0, stream>>>(ws);
  k4_mean<<<36, 256, 0, stream>>>(ws);
  k5_norm<<<(2 * L + 255) / 256, 256, 0, stream>>>(ws);
  k6_topk<<<2 * NROWBLK * NS, TMAIN, 0, stream>>>(ws);
  k7a_groups<<<(2 * L + 255) / 256, 256, 0, stream>>>(ws);
  k7b_recover<<<(2 * L + 255) / 256, 256, 0, stream>>>(ws);
  k8_fold<<<(2 * KTOP * PSZ * PSZ + 255) / 256, 256, 0, stream>>>(ws, out);
}

// Round 8
// 238.356 us; speedup vs baseline: 1.0256x; 1.0256x over previous
//
#include <hip/hip_runtime.h>
#include <math.h>
#include <float.h>

#define PSZ 256
#define NPATCH 127
#define L 16129            // 127*127
#define KTOP 4
#define TMAIN 256
#define RPT 2              // rows per thread
#define ROWS_PER_BLOCK (TMAIN * RPT)   // 512
#define NROWBLK 32                     // 32*512 = 16384 >= L
#define NS 32
#define SEGLEN 505                     // ceil(L/32)
#define MSTRIDE 508                    // float4-aligned LDS stride
#define ROWPAD 16384
#define GRP 8                          // tournament group size

typedef float f2 __attribute__((ext_vector_type(2)));

// packed f32 math (2 independent IEEE FMAs; bit-exact per element).
// Register-only asm: data deps explicit through operands, scheduler-safe.
__device__ __forceinline__ f2 pk_fma(f2 a, f2 b, f2 c) {
  f2 d;
  asm("v_pk_fma_f32 %0, %1, %2, %3" : "=v"(d) : "v"(a), "v"(b), "v"(c));
  return d;
}
__device__ __forceinline__ f2 pk_mul(f2 a, f2 b) {
  f2 d;
  asm("v_pk_mul_f32 %0, %1, %2" : "=v"(d) : "v"(a), "v"(b));
  return d;
}

// ---- workspace layout (float elements) ----
static constexpr size_t OFF_CMAX = 0;                          // [2][256][256]
static constexpr size_t OFF_CMIN = OFF_CMAX + 2 * PSZ * PSZ;
static constexpr size_t OFF_REFG = OFF_CMIN + 2 * PSZ * PSZ;
static constexpr size_t OFF_XG   = OFF_REFG + 2 * PSZ * PSZ;
static constexpr size_t OFF_MUI  = OFF_XG   + 2 * PSZ * PSZ;   // [18]
static constexpr size_t OFF_MUR  = OFF_MUI  + 20;
static constexpr size_t OFF_A    = OFF_MUR  + 20;              // [2][L][9] input_norm
static constexpr size_t OFF_B    = OFF_A    + 290324;          // [2][9][L] ref_norm (p-major)
static constexpr size_t OFF_BT   = OFF_B    + 290324;          // [2][L][9] ref_norm (m-major)
static constexpr size_t OFF_IDX  = OFF_BT   + 290324;          // [2][L][4] final idx (int)
static constexpr size_t OFF_PV   = OFF_IDX  + 2 * L * 4;       // [2][NS][ROWPAD][4] group-max vals
static constexpr size_t OFF_PI   = OFF_PV   + (size_t)2 * NS * ROWPAD * 4;  // group bases (int)
// end ~= 10.0M floats (40.1 MB) <= 41.07 MB proven present (round 2 NS=32 layout ran).

// insert (rm, gb) into sorted-desc; strict > keeps earlier entry on ties
// (candidates arrive in ascending gb).
__device__ __forceinline__ void insg(float rm, int gb,
    float& g0, float& g1, float& g2, float& g3,
    int& i0, int& i1, int& i2, int& i3) {
  bool c0 = rm > g0, c1 = rm > g1, c2 = rm > g2, c3 = rm > g3;
  g3 = c2 ? g2 : (c3 ? rm : g3);  i3 = c2 ? i2 : (c3 ? gb : i3);
  g2 = c1 ? g1 : (c2 ? rm : g2);  i2 = c1 ? i1 : (c2 ? gb : i2);
  g1 = c0 ? g0 : (c1 ? rm : g1);  i1 = c0 ? i0 : (c1 ? gb : i1);
  g0 = c0 ? rm : g0;              i0 = c0 ? gb : i0;
}

// composite-order insert: (v desc, m asc); order-independent, duplicate-safe.
__device__ __forceinline__ void ins4c(float v, int m,
    float& v0, float& v1, float& v2, float& v3,
    int& x0, int& x1, int& x2, int& x3) {
  bool c0 = (v > v0) || (v == v0 && m < x0);
  bool c1 = (v > v1) || (v == v1 && m < x1);
  bool c2 = (v > v2) || (v == v2 && m < x2);
  bool c3 = (v > v3) || (v == v3 && m < x3);
  v3 = c2 ? v2 : (c3 ? v : v3);  x3 = c2 ? x2 : (c3 ? m : x3);
  v2 = c1 ? v1 : (c2 ? v : v2);  x2 = c1 ? x1 : (c2 ? m : x2);
  v1 = c0 ? v0 : (c1 ? v : v1);  x1 = c0 ? x0 : (c1 ? m : x1);
  v0 = c0 ? v : v0;              x0 = c0 ? m : x0;
}

// k1: per pixel: channel max/min of x, channel mean of ref, copy x -> out[:, :3]
__global__ void k1_pixel(const float* __restrict__ x, const float* __restrict__ ref,
                         float* __restrict__ ws, float* __restrict__ out) {
  int id = blockIdx.x * 256 + threadIdx.x;
  if (id >= 2 * PSZ * PSZ) return;
  int b = id >> 16;
  int pix = id & 0xFFFF;
  const float* xb = x + (size_t)b * 3 * PSZ * PSZ + pix;
  float c0 = xb[0], c1 = xb[PSZ * PSZ], c2 = xb[2 * PSZ * PSZ];
  ws[OFF_CMAX + id] = fmaxf(fmaxf(c0, c1), c2);
  ws[OFF_CMIN + id] = fminf(fminf(c0, c1), c2);
  const float* rb = ref + (size_t)b * 3 * PSZ * PSZ + pix;
  ws[OFF_REFG + id] = (rb[0] + rb[PSZ * PSZ] + rb[2 * PSZ * PSZ]) / 3.0f;
  float* ob = out + (size_t)b * 7 * PSZ * PSZ + pix;
  ob[0] = c0; ob[PSZ * PSZ] = c1; ob[2 * PSZ * PSZ] = c2;
}

// k2: x_gray = 3x3 clipped-window max of cmax - cmin
__global__ void k2_gray(float* __restrict__ ws) {
  int id = blockIdx.x * 256 + threadIdx.x;
  if (id >= 2 * PSZ * PSZ) return;
  int b = id >> 16;
  int pix = id & 0xFFFF;
  int y = pix >> 8, xx = pix & 255;
  const float* cm = ws + OFF_CMAX + ((size_t)b << 16);
  float m = -3.402823466e+38f;
  for (int dy = -1; dy <= 1; ++dy) {
    int yy = y + dy;
    if (yy < 0 || yy > 255) continue;
    for (int dx = -1; dx <= 1; ++dx) {
      int xc = xx + dx;
      if (xc < 0 || xc > 255) continue;
      m = fmaxf(m, cm[yy * PSZ + xc]);
    }
  }
  ws[OFF_XG + id] = m - ws[OFF_CMIN + id];
}

// k4: per-(which,b,p) mean over L in f64. 36 blocks x 1024 threads,
// 16 elems/thread with incremental (i,j) -- no per-element div/mod.
__global__ void k4_mean(float* __restrict__ ws) {
  __shared__ double sm[1024];
  int which = blockIdx.x / 18;  // 0 = input(xg), 1 = ref(rg)
  int bp = blockIdx.x % 18;
  int b = bp / 9, p = bp % 9;
  int di = p / 3, dj = p % 3;
  const float* g = ws + (which ? OFF_REFG : OFF_XG) + ((size_t)b << 16);
  int t = threadIdx.x;
  double s = 0.0;
  int l0 = t * 16;
  if (l0 < L) {
    int l1 = l0 + 16 < L ? l0 + 16 : L;
    int i = l0 / NPATCH, j = l0 % NPATCH;
    for (int l = l0; l < l1; ++l) {
      s += (double)g[(2 * i + di) * PSZ + 2 * j + dj];
      if (++j == NPATCH) { j = 0; ++i; }
    }
  }
  sm[t] = s;
  __syncthreads();
  for (int st = 512; st > 0; st >>= 1) {
    if (t < st) sm[t] += sm[t + st];
    __syncthreads();
  }
  if (t == 0)
    ws[(which ? OFF_MUR : OFF_MUI) + bp] = (float)(sm[0] / (double)L);
}

// k5: per l compute patch values + uncentered norms, then
// A[b][l][9] = (ip - muI)/nI ; B[b][9][L] and BT[b][l][9] = (rp - muR)/nR
__global__ void k5_norm(float* __restrict__ ws) {
  int id = blockIdx.x * 256 + threadIdx.x;
  if (id >= 2 * L) return;
  int b = id / L, l = id % L;
  int i = l / NPATCH, j = l % NPATCH;
  const float* xg = ws + OFF_XG + ((size_t)b << 16);
  const float* rg = ws + OFF_REFG + ((size_t)b << 16);
  float vi[9], vr[9];
  float si = 0.f, sr = 0.f;
#pragma unroll
  for (int p = 0; p < 9; ++p) {
    int di = p / 3, dj = p % 3;
    vi[p] = xg[(2 * i + di) * PSZ + 2 * j + dj];
    vr[p] = rg[(2 * i + di) * PSZ + 2 * j + dj];
    si += vi[p] * vi[p];
    sr += vr[p] * vr[p];
  }
  float ni = sqrtf(si), nr = sqrtf(sr);
#pragma unroll
  for (int p = 0; p < 9; ++p) {
    float mi = ws[OFF_MUI + b * 9 + p];
    float mr = ws[OFF_MUR + b * 9 + p];
    float bn = (vr[p] - mr) / nr;
    ws[OFF_A + ((size_t)b * L + l) * 9 + p] = (vi[p] - mi) / ni;
    ws[OFF_B + ((size_t)b * 9 + p) * L + l] = bn;
    ws[OFF_BT + ((size_t)b * L + l) * 9 + p] = bn;
  }
}

// k6: fused ncc + per-(row,segment) top-4 GROUP-MAX tournament, pk-f32 math.
// grid: 2 x 32(rowblk) x 32(seg) = 2048 blocks, 256 threads, 2 rows/thread,
// 8 m/iter. launch_bounds(256,1): empirical cap model 512/(4*arg2) -> 128
// VGPR; demand ~84 (va/vb pairs 36 + accums 16 + top4 16 + addr) -> no spill.
__global__ __launch_bounds__(TMAIN, 1) void k6_topk(float* __restrict__ ws) {
  __shared__ float lds[9 * MSTRIDE];  // 18288 B

  int bid = blockIdx.x;
  int seg = bid % NS;
  int rowblk = (bid / NS) % NROWBLK;
  int b = bid / (NS * NROWBLK);
  int m0 = seg * SEGLEN;
  int mend = m0 + SEGLEN;
  if (mend > L) mend = L;
  int mlen = mend - m0;

  const float* Bg = ws + OFF_B + (size_t)b * 9 * L + m0;
  for (int p = 0; p < 9; ++p)
    for (int mm = threadIdx.x; mm < mlen; mm += TMAIN)
      lds[p * MSTRIDE + mm] = Bg[(size_t)p * L + mm];
  __syncthreads();

  int row0 = rowblk * ROWS_PER_BLOCK + threadIdx.x * RPT;
  int r0 = row0 < L - 1 ? row0 : L - 1;
  int r1 = row0 + 1 < L - 1 ? row0 + 1 : L - 1;
  f2 va[9], vb[9];  // broadcast pairs, loop-invariant
  {
    const float* Ap0 = ws + OFF_A + ((size_t)b * L + r0) * 9;
    const float* Ap1 = ws + OFF_A + ((size_t)b * L + r1) * 9;
#pragma unroll
    for (int p = 0; p < 9; ++p) {
      float a0 = Ap0[p], a1 = Ap1[p];
      va[p].x = a0; va[p].y = a0;
      vb[p].x = a1; vb[p].y = a1;
    }
  }

  float g00 = -FLT_MAX, g01 = g00, g02 = g00, g03 = g00;
  float g10 = g00, g11 = g00, g12 = g00, g13 = g00;
  int i00 = 0, i01 = 0, i02 = 0, i03 = 0;
  int i10 = 0, i11 = 0, i12 = 0, i13 = 0;

  int ngrp = mlen >> 3;  // full groups of 8
  for (int g = 0; g < ngrp; ++g) {
    int mm = g << 3;
    f2 s0a, s0b, s0c, s0d, s1a, s1b, s1c, s1d;
#pragma unroll
    for (int p = 0; p < 9; ++p) {
      const float4* bp4 = reinterpret_cast<const float4*>(&lds[p * MSTRIDE + mm]);
      float4 q0 = bp4[0], q1 = bp4[1];
      f2 b0 = {q0.x, q0.y}, b1 = {q0.z, q0.w};
      f2 b2 = {q1.x, q1.y}, b3 = {q1.z, q1.w};
      if (p == 0) {
        s0a = pk_mul(va[0], b0); s0b = pk_mul(va[0], b1);
        s0c = pk_mul(va[0], b2); s0d = pk_mul(va[0], b3);
        s1a = pk_mul(vb[0], b0); s1b = pk_mul(vb[0], b1);
        s1c = pk_mul(vb[0], b2); s1d = pk_mul(vb[0], b3);
      } else {
        s0a = pk_fma(va[p], b0, s0a); s0b = pk_fma(va[p], b1, s0b);
        s0c = pk_fma(va[p], b2, s0c); s0d = pk_fma(va[p], b3, s0d);
        s1a = pk_fma(vb[p], b0, s1a); s1b = pk_fma(vb[p], b1, s1b);
        s1c = pk_fma(vb[p], b2, s1c); s1d = pk_fma(vb[p], b3, s1d);
      }
    }
    float rm0 = fmaxf(fmaxf(fmaxf(s0a.x, s0a.y), fmaxf(s0b.x, s0b.y)),
                      fmaxf(fmaxf(s0c.x, s0c.y), fmaxf(s0d.x, s0d.y)));
    float rm1 = fmaxf(fmaxf(fmaxf(s1a.x, s1a.y), fmaxf(s1b.x, s1b.y)),
                      fmaxf(fmaxf(s1c.x, s1c.y), fmaxf(s1d.x, s1d.y)));
    int gb = m0 + mm;
    insg(rm0, gb, g00, g01, g02, g03, i00, i01, i02, i03);
    insg(rm1, gb, g10, g11, g12, g13, i10, i11, i12, i13);
  }
  // tail (< 8 m): one partial group (recovery scan is clip-safe).
  int tb = ngrp << 3;
  if (tb < mlen) {
    float rt0 = -FLT_MAX, rt1 = -FLT_MAX;
    for (int mm = tb; mm < mlen; ++mm) {
      float bb = lds[mm];
      float sv0 = va[0].x * bb, sv1 = vb[0].x * bb;
#pragma unroll
      for (int p = 1; p < 9; ++p) {
        bb = lds[p * MSTRIDE + mm];
        sv0 = fmaf(va[p].x, bb, sv0); sv1 = fmaf(vb[p].x, bb, sv1);
      }
      rt0 = fmaxf(rt0, sv0); rt1 = fmaxf(rt1, sv1);
    }
    insg(rt0, m0 + tb, g00, g01, g02, g03, i00, i01, i02, i03);
    insg(rt1, m0 + tb, g10, g11, g12, g13, i10, i11, i12, i13);
  }

  int* wsi = (int*)ws;
  if (row0 < L) {
    size_t base = (((size_t)b * NS + seg) * ROWPAD + row0) * 4;
    ws[OFF_PV + base + 0] = g00; ws[OFF_PV + base + 1] = g01;
    ws[OFF_PV + base + 2] = g02; ws[OFF_PV + base + 3] = g03;
    wsi[OFF_PI + base + 0] = i00; wsi[OFF_PI + base + 1] = i01;
    wsi[OFF_PI + base + 2] = i02; wsi[OFF_PI + base + 3] = i03;
  }
  if (row0 + 1 < L) {
    size_t base = (((size_t)b * NS + seg) * ROWPAD + row0 + 1) * 4;
    ws[OFF_PV + base + 0] = g10; ws[OFF_PV + base + 1] = g11;
    ws[OFF_PV + base + 2] = g12; ws[OFF_PV + base + 3] = g13;
    wsi[OFF_PI + base + 0] = i10; wsi[OFF_PI + base + 1] = i11;
    wsi[OFF_PI + base + 2] = i12; wsi[OFF_PI + base + 3] = i13;
  }
}

// k7 (fused k7a+k7b): per row, merge 32 segs x 4 (group-max, base) ->
// top-4 groups by (max desc, base asc), then rescan those groups (<= 32 m,
// boundary-crossing duplicate-safe) with the identical fmaf chain -> exact
// composite top-4 -> IDX.
__global__ void k7_merge(float* __restrict__ ws) {
  int id = blockIdx.x * 256 + threadIdx.x;
  if (id >= 2 * L) return;
  int b = id / L, row = id % L;
  const int* wsi_c = (const int*)ws;

  float v0 = -FLT_MAX, v1 = v0, v2 = v0, v3 = v0;
  int x0 = 0x7FFFFFFF, x1 = x0, x2 = x0, x3 = x0;
  for (int s = 0; s < NS; ++s) {
    size_t base = (((size_t)b * NS + s) * ROWPAD + row) * 4;
#pragma unroll
    for (int q = 0; q < 4; ++q) {
      float val = ws[OFF_PV + base + q];
      int gb = wsi_c[OFF_PI + base + q];
      ins4c(val, gb, v0, v1, v2, v3, x0, x1, x2, x3);
    }
  }

  float a[9];
  const float* Ap = ws + OFF_A + ((size_t)b * L + row) * 9;
#pragma unroll
  for (int p = 0; p < 9; ++p) a[p] = Ap[p];

  int gbs[4] = {x0, x1, x2, x3};
  float w0 = -FLT_MAX, w1 = w0, w2 = w0, w3 = w0;
  int y0 = 0x7FFFFFFF, y1 = y0, y2 = y0, y3 = y0;
#pragma unroll
  for (int slot = 0; slot < 4; ++slot) {
    int gb = gbs[slot];
    int ge = gb + GRP; if (ge > L) ge = L;
    for (int mm = gb; mm < ge; ++mm) {
      const float* bt = ws + OFF_BT + ((size_t)b * L + mm) * 9;
      float s = a[0] * bt[0];
#pragma unroll
      for (int p = 1; p < 9; ++p) s = fmaf(a[p], bt[p], s);
      ins4c(s, mm, w0, w1, w2, w3, y0, y1, y2, y3);
    }
  }
  int* wsi = (int*)ws;
  size_t ib = OFF_IDX + (size_t)id * 4;
  wsi[ib] = y0; wsi[ib + 1] = y1; wsi[ib + 2] = y2; wsi[ib + 3] = y3;
}

// k8: fold (overlap-add) via per-output-pixel gather; reads ref_gray directly
__global__ void k8_fold(const float* __restrict__ ws, float* __restrict__ out) {
  int id = blockIdx.x * 256 + threadIdx.x;
  if (id >= 2 * KTOP * PSZ * PSZ) return;
  int b = id / (KTOP * PSZ * PSZ);
  int rem = id % (KTOP * PSZ * PSZ);
  int kk = rem >> 16;
  int pix = rem & 0xFFFF;
  int y = pix >> 8, xx = pix & 255;
  const int* wsi = (const int*)ws;
  const float* rg = ws + OFF_REFG + ((size_t)b << 16);
  float acc = 0.f;
  for (int di = 0; di < 3; ++di) {
    int yy = y - di;
    if (yy < 0 || (yy & 1) || (yy >> 1) >= NPATCH) continue;
    int i = yy >> 1;
    for (int dj = 0; dj < 3; ++dj) {
      int xc = xx - dj;
      if (xc < 0 || (xc & 1) || (xc >> 1) >= NPATCH) continue;
      int j = xc >> 1;
      int l = i * NPATCH + j;
      int m = wsi[OFF_IDX + ((size_t)b * L + l) * 4 + kk];
      int mi = m / NPATCH, mj = m % NPATCH;
      acc += rg[(2 * mi + di) * PSZ + 2 * mj + dj];
    }
  }
  out[(((size_t)b * 7 + 3 + kk) * PSZ + y) * PSZ + xx] = acc;
}

extern "C" void kernel_launch(void* const* d_in, const int* in_sizes, int n_in,
                              void* d_out, int out_size, void* d_ws, size_t ws_size,
                              hipStream_t stream) {
  const float* x = (const float*)d_in[0];
  const float* ref = (const float*)d_in[1];
  float* ws = (float*)d_ws;
  float* out = (float*)d_out;

  k1_pixel<<<512, 256, 0, stream>>>(x, ref, ws, out);
  k2_gray<<<512, 256, 0, stream>>>(ws);
  k4_mean<<<36, 1024, 0, stream>>>(ws);
  k5_norm<<<(2 * L + 255) / 256, 256, 0, stream>>>(ws);
  k6_topk<<<2 * NROWBLK * NS, TMAIN, 0, stream>>>(ws);
  k7_merge<<<(2 * L + 255) / 256, 256, 0, stream>>>(ws);
  k8_fold<<<(2 * KTOP * PSZ * PSZ + 255) / 256, 256, 0, stream>>>(ws, out);
}

// Round 10
// 231.509 us; speedup vs baseline: 1.0559x; 1.0296x over previous
//
#include <hip/hip_runtime.h>
#include <math.h>
#include <float.h>

#define PSZ 256
#define NPATCH 127
#define L 16129            // 127*127
#define KTOP 4
#define TMAIN 256
#define RPT 2              // rows per thread
#define ROWS_PER_BLOCK (TMAIN * RPT)   // 512
#define NROWBLK 32                     // 32*512 = 16384 >= L
#define NS 32
#define SEGLEN 505                     // ceil(L/32)
#define MSTRIDE 508                    // float4-aligned LDS stride
#define ROWPAD 16384
#define GRP 16                         // tournament group size (m's per group)

// ---- workspace layout (float elements) ----
static constexpr size_t OFF_REFG = 0;                          // [2][256][256]
static constexpr size_t OFF_XG   = OFF_REFG + 2 * PSZ * PSZ;
static constexpr size_t OFF_MUI  = OFF_XG   + 2 * PSZ * PSZ;   // [18]
static constexpr size_t OFF_MUR  = OFF_MUI  + 20;
static constexpr size_t OFF_A    = OFF_MUR  + 20;              // [2][L][9] input_norm
static constexpr size_t OFF_B    = OFF_A    + 290324;          // [2][9][L] ref_norm (p-major)
static constexpr size_t OFF_BT   = OFF_B    + 290324;          // [2][L][9] ref_norm (m-major)
static constexpr size_t OFF_IDX  = OFF_BT   + 290324;          // [2][L][4] final idx (int)
static constexpr size_t OFF_PV   = OFF_IDX  + 2 * L * 4;       // [2][NS][ROWPAD][4] group-max vals
static constexpr size_t OFF_PI   = OFF_PV   + (size_t)2 * NS * ROWPAD * 4;  // group bases (int)
// end ~= 9.8M floats (39.1 MB) <= 41.07 MB proven present (round 2 NS=32 layout ran).

// insert (rm, gb) into sorted-desc; strict > keeps earlier entry on ties
// (candidates arrive in ascending gb). Each group inserted exactly once.
__device__ __forceinline__ void insg(float rm, int gb,
    float& g0, float& g1, float& g2, float& g3,
    int& i0, int& i1, int& i2, int& i3) {
  bool c0 = rm > g0, c1 = rm > g1, c2 = rm > g2, c3 = rm > g3;
  g3 = c2 ? g2 : (c3 ? rm : g3);  i3 = c2 ? i2 : (c3 ? gb : i3);
  g2 = c1 ? g1 : (c2 ? rm : g2);  i2 = c1 ? i1 : (c2 ? gb : i2);
  g1 = c0 ? g0 : (c1 ? rm : g1);  i1 = c0 ? i0 : (c1 ? gb : i1);
  g0 = c0 ? rm : g0;              i0 = c0 ? gb : i0;
}

// composite-order insert: (v desc, m asc). NOT duplicate-safe (re-inserting
// an element clones it one slot down) -- callers must feed DISTINCT (v,m)
// candidates. k7's rescan ranges are disjoint by construction (round-9 fix).
__device__ __forceinline__ void ins4c(float v, int m,
    float& v0, float& v1, float& v2, float& v3,
    int& x0, int& x1, int& x2, int& x3) {
  bool c0 = (v > v0) || (v == v0 && m < x0);
  bool c1 = (v > v1) || (v == v1 && m < x1);
  bool c2 = (v > v2) || (v == v2 && m < x2);
  bool c3 = (v > v3) || (v == v3 && m < x3);
  v3 = c2 ? v2 : (c3 ? v : v3);  x3 = c2 ? x2 : (c3 ? m : x3);
  v2 = c1 ? v1 : (c2 ? v : v2);  x2 = c1 ? x1 : (c2 ? m : x2);
  v1 = c0 ? v0 : (c1 ? v : v1);  x1 = c0 ? x0 : (c1 ? m : x1);
  v0 = c0 ? v : v0;              x0 = c0 ? m : x0;
}

// k12 (fused k1+k2): per 32x32 tile with 1-px halo in LDS:
// XG = 3x3 clipped-window max of channel-max(x) - channel-min(x);
// REFG = channel-mean(ref); copy x -> out[:, :3].
__global__ void k12_gray(const float* __restrict__ x, const float* __restrict__ ref,
                         float* __restrict__ ws, float* __restrict__ out) {
  __shared__ float sm[34][35];
  int tile = blockIdx.x & 63;        // 8x8 tiles of 32x32
  int b = blockIdx.x >> 6;
  int ty0 = (tile >> 3) << 5, tx0 = (tile & 7) << 5;
  const float* xb = x + (size_t)b * 3 * 65536;
  const float* rb = ref + (size_t)b * 3 * 65536;
  for (int hid = threadIdx.x; hid < 34 * 34; hid += 256) {
    int hy = hid / 34, hx = hid % 34;
    int gy = ty0 + hy - 1, gx = tx0 + hx - 1;
    float m = -FLT_MAX;
    if (gy >= 0 && gy < 256 && gx >= 0 && gx < 256) {
      int pix = gy * 256 + gx;
      m = fmaxf(fmaxf(xb[pix], xb[65536 + pix]), xb[131072 + pix]);
    }
    sm[hy][hx] = m;
  }
  __syncthreads();
  for (int iid = threadIdx.x; iid < 1024; iid += 256) {
    int iy = iid >> 5, ix = iid & 31;
    int gy = ty0 + iy, gx = tx0 + ix;
    int pix = gy * 256 + gx;
    float c0 = xb[pix], c1 = xb[65536 + pix], c2 = xb[131072 + pix];
    float cmin = fminf(fminf(c0, c1), c2);
    float mx = sm[iy][ix];
#pragma unroll
    for (int dy = 0; dy < 3; ++dy)
#pragma unroll
      for (int dx = 0; dx < 3; ++dx)
        mx = fmaxf(mx, sm[iy + dy][ix + dx]);
    size_t id = ((size_t)b << 16) + pix;
    ws[OFF_XG + id] = mx - cmin;
    ws[OFF_REFG + id] = (rb[pix] + rb[65536 + pix] + rb[131072 + pix]) / 3.0f;
    float* ob = out + (size_t)b * 7 * 65536 + pix;
    ob[0] = c0; ob[65536] = c1; ob[131072] = c2;
  }
}

// k4: per-(which,b,p) mean over L in f64. 36 blocks x 1024 threads,
// 16 elems/thread with incremental (i,j).
__global__ void k4_mean(float* __restrict__ ws) {
  __shared__ double sm[1024];
  int which = blockIdx.x / 18;  // 0 = input(xg), 1 = ref(rg)
  int bp = blockIdx.x % 18;
  int b = bp / 9, p = bp % 9;
  int di = p / 3, dj = p % 3;
  const float* g = ws + (which ? OFF_REFG : OFF_XG) + ((size_t)b << 16);
  int t = threadIdx.x;
  double s = 0.0;
  int l0 = t * 16;
  if (l0 < L) {
    int l1 = l0 + 16 < L ? l0 + 16 : L;
    int i = l0 / NPATCH, j = l0 % NPATCH;
    for (int l = l0; l < l1; ++l) {
      s += (double)g[(2 * i + di) * PSZ + 2 * j + dj];
      if (++j == NPATCH) { j = 0; ++i; }
    }
  }
  sm[t] = s;
  __syncthreads();
  for (int st = 512; st > 0; st >>= 1) {
    if (t < st) sm[t] += sm[t + st];
    __syncthreads();
  }
  if (t == 0)
    ws[(which ? OFF_MUR : OFF_MUI) + bp] = (float)(sm[0] / (double)L);
}

// k5: per l compute patch values + uncentered norms, then
// A[b][l][9] = (ip - muI)/nI ; B[b][9][L] and BT[b][l][9] = (rp - muR)/nR
__global__ void k5_norm(float* __restrict__ ws) {
  int id = blockIdx.x * 256 + threadIdx.x;
  if (id >= 2 * L) return;
  int b = id / L, l = id % L;
  int i = l / NPATCH, j = l % NPATCH;
  const float* xg = ws + OFF_XG + ((size_t)b << 16);
  const float* rg = ws + OFF_REFG + ((size_t)b << 16);
  float vi[9], vr[9];
  float si = 0.f, sr = 0.f;
#pragma unroll
  for (int p = 0; p < 9; ++p) {
    int di = p / 3, dj = p % 3;
    vi[p] = xg[(2 * i + di) * PSZ + 2 * j + dj];
    vr[p] = rg[(2 * i + di) * PSZ + 2 * j + dj];
    si += vi[p] * vi[p];
    sr += vr[p] * vr[p];
  }
  float ni = sqrtf(si), nr = sqrtf(sr);
#pragma unroll
  for (int p = 0; p < 9; ++p) {
    float mi = ws[OFF_MUI + b * 9 + p];
    float mr = ws[OFF_MUR + b * 9 + p];
    float bn = (vr[p] - mr) / nr;
    ws[OFF_A + ((size_t)b * L + l) * 9 + p] = (vi[p] - mi) / ni;
    ws[OFF_B + ((size_t)b * 9 + p) * L + l] = bn;
    ws[OFF_BT + ((size_t)b * L + l) * 9 + p] = bn;
  }
}

// k6: fused ncc + per-(row,segment) top-4 GROUP-MAX tournament, groups of 16 m,
// incremental row-max. Group-max coverage is strictly IN-SEGMENT (tail group
// covers only [tb, mlen)); k7 rescans with matching segment-clipped ranges.
// grid: 2 x 32(rowblk) x 32(seg) = 2048 blocks, 256 threads, 2 rows/thread.
__global__ __launch_bounds__(TMAIN, 2) void k6_topk(float* __restrict__ ws) {
  __shared__ float lds[9 * MSTRIDE];  // 18288 B

  int bid = blockIdx.x;
  int seg = bid % NS;
  int rowblk = (bid / NS) % NROWBLK;
  int b = bid / (NS * NROWBLK);
  int m0 = seg * SEGLEN;
  int mend = m0 + SEGLEN;
  if (mend > L) mend = L;
  int mlen = mend - m0;

  const float* Bg = ws + OFF_B + (size_t)b * 9 * L + m0;
  for (int p = 0; p < 9; ++p)
    for (int mm = threadIdx.x; mm < mlen; mm += TMAIN)
      lds[p * MSTRIDE + mm] = Bg[(size_t)p * L + mm];
  __syncthreads();

  int row0 = rowblk * ROWS_PER_BLOCK + threadIdx.x * RPT;
  int r0 = row0 < L - 1 ? row0 : L - 1;
  int r1 = row0 + 1 < L - 1 ? row0 + 1 : L - 1;
  float a0[9], a1[9];
  {
    const float* Ap0 = ws + OFF_A + ((size_t)b * L + r0) * 9;
    const float* Ap1 = ws + OFF_A + ((size_t)b * L + r1) * 9;
#pragma unroll
    for (int p = 0; p < 9; ++p) { a0[p] = Ap0[p]; a1[p] = Ap1[p]; }
  }

  float g00 = -FLT_MAX, g01 = g00, g02 = g00, g03 = g00;
  float g10 = g00, g11 = g00, g12 = g00, g13 = g00;
  int i00 = 0, i01 = 0, i02 = 0, i03 = 0;
  int i10 = 0, i11 = 0, i12 = 0, i13 = 0;

  int nfull = mlen >> 4;  // full groups of 16
  for (int g = 0; g < nfull; ++g) {
    int mm = g << 4;
    float rm0 = -FLT_MAX, rm1 = -FLT_MAX;
#pragma unroll
    for (int q = 0; q < 4; ++q) {
      float s00, s01, s02, s03, s10, s11, s12, s13;
#pragma unroll
      for (int p = 0; p < 9; ++p) {
        const float4 bq = *reinterpret_cast<const float4*>(&lds[p * MSTRIDE + mm + q * 4]);
        if (p == 0) {
          s00 = a0[0] * bq.x; s01 = a0[0] * bq.y; s02 = a0[0] * bq.z; s03 = a0[0] * bq.w;
          s10 = a1[0] * bq.x; s11 = a1[0] * bq.y; s12 = a1[0] * bq.z; s13 = a1[0] * bq.w;
        } else {
          s00 = fmaf(a0[p], bq.x, s00); s01 = fmaf(a0[p], bq.y, s01);
          s02 = fmaf(a0[p], bq.z, s02); s03 = fmaf(a0[p], bq.w, s03);
          s10 = fmaf(a1[p], bq.x, s10); s11 = fmaf(a1[p], bq.y, s11);
          s12 = fmaf(a1[p], bq.z, s12); s13 = fmaf(a1[p], bq.w, s13);
        }
      }
      rm0 = fmaxf(rm0, fmaxf(fmaxf(s00, s01), fmaxf(s02, s03)));
      rm1 = fmaxf(rm1, fmaxf(fmaxf(s10, s11), fmaxf(s12, s13)));
    }
    int gb = m0 + mm;
    insg(rm0, gb, g00, g01, g02, g03, i00, i01, i02, i03);
    insg(rm1, gb, g10, g11, g12, g13, i10, i11, i12, i13);
  }
  // tail (< 16 m, in-segment only)
  int tb = nfull << 4;
  if (tb < mlen) {
    float rt0 = -FLT_MAX, rt1 = -FLT_MAX;
    for (int mm = tb; mm < mlen; ++mm) {
      float bb = lds[mm];
      float sv0 = a0[0] * bb, sv1 = a1[0] * bb;
#pragma unroll
      for (int p = 1; p < 9; ++p) {
        bb = lds[p * MSTRIDE + mm];
        sv0 = fmaf(a0[p], bb, sv0); sv1 = fmaf(a1[p], bb, sv1);
      }
      rt0 = fmaxf(rt0, sv0); rt1 = fmaxf(rt1, sv1);
    }
    insg(rt0, m0 + tb, g00, g01, g02, g03, i00, i01, i02, i03);
    insg(rt1, m0 + tb, g10, g11, g12, g13, i10, i11, i12, i13);
  }

  int* wsi = (int*)ws;
  if (row0 < L) {
    size_t base = (((size_t)b * NS + seg) * ROWPAD + row0) * 4;
    ws[OFF_PV + base + 0] = g00; ws[OFF_PV + base + 1] = g01;
    ws[OFF_PV + base + 2] = g02; ws[OFF_PV + base + 3] = g03;
    wsi[OFF_PI + base + 0] = i00; wsi[OFF_PI + base + 1] = i01;
    wsi[OFF_PI + base + 2] = i02; wsi[OFF_PI + base + 3] = i03;
  }
  if (row0 + 1 < L) {
    size_t base = (((size_t)b * NS + seg) * ROWPAD + row0 + 1) * 4;
    ws[OFF_PV + base + 0] = g10; ws[OFF_PV + base + 1] = g11;
    ws[OFF_PV + base + 2] = g12; ws[OFF_PV + base + 3] = g13;
    wsi[OFF_PI + base + 0] = i10; wsi[OFF_PI + base + 1] = i11;
    wsi[OFF_PI + base + 2] = i12; wsi[OFF_PI + base + 3] = i13;
  }
}

// k7: per row, merge 32 segs x 4 (group-max, base) -> top-4 groups by
// (max desc, base asc), then rescan those groups with ranges CLIPPED TO THE
// SEGMENT END (= exactly k6's group coverage; disjoint, so no duplicate
// inserts -- the round-9 corruption was cross-segment rescan overlap).
__global__ void k7_merge(float* __restrict__ ws) {
  int id = blockIdx.x * 256 + threadIdx.x;
  if (id >= 2 * L) return;
  int b = id / L, row = id % L;
  const int* wsi_c = (const int*)ws;

  float v0 = -FLT_MAX, v1 = v0, v2 = v0, v3 = v0;
  int x0 = 0x7FFFFFFF, x1 = x0, x2 = x0, x3 = x0;
  for (int s = 0; s < NS; ++s) {
    size_t base = (((size_t)b * NS + s) * ROWPAD + row) * 4;
#pragma unroll
    for (int q = 0; q < 4; ++q) {
      float val = ws[OFF_PV + base + q];
      int gb = wsi_c[OFF_PI + base + q];
      ins4c(val, gb, v0, v1, v2, v3, x0, x1, x2, x3);
    }
  }

  float a[9];
  const float* Ap = ws + OFF_A + ((size_t)b * L + row) * 9;
#pragma unroll
  for (int p = 0; p < 9; ++p) a[p] = Ap[p];

  int gbs[4] = {x0, x1, x2, x3};
  float w0 = -FLT_MAX, w1 = w0, w2 = w0, w3 = w0;
  int y0 = 0x7FFFFFFF, y1 = y0, y2 = y0, y3 = y0;
#pragma unroll
  for (int slot = 0; slot < 4; ++slot) {
    int gb = gbs[slot];
    int se = (gb / SEGLEN + 1) * SEGLEN;   // owning segment's end
    int ge = gb + GRP;
    if (ge > se) ge = se;
    if (ge > L) ge = L;
    for (int mm = gb; mm < ge; ++mm) {
      const float* bt = ws + OFF_BT + ((size_t)b * L + mm) * 9;
      float s = a[0] * bt[0];
#pragma unroll
      for (int p = 1; p < 9; ++p) s = fmaf(a[p], bt[p], s);
      ins4c(s, mm, w0, w1, w2, w3, y0, y1, y2, y3);
    }
  }
  int* wsi = (int*)ws;
  size_t ib = OFF_IDX + (size_t)id * 4;
  wsi[ib] = y0; wsi[ib + 1] = y1; wsi[ib + 2] = y2; wsi[ib + 3] = y3;
}

// k8: fold (overlap-add) via per-output-pixel gather; reads ref_gray directly
__global__ void k8_fold(const float* __restrict__ ws, float* __restrict__ out) {
  int id = blockIdx.x * 256 + threadIdx.x;
  if (id >= 2 * KTOP * PSZ * PSZ) return;
  int b = id / (KTOP * PSZ * PSZ);
  int rem = id % (KTOP * PSZ * PSZ);
  int kk = rem >> 16;
  int pix = rem & 0xFFFF;
  int y = pix >> 8, xx = pix & 255;
  const int* wsi = (const int*)ws;
  const float* rg = ws + OFF_REFG + ((size_t)b << 16);
  float acc = 0.f;
  for (int di = 0; di < 3; ++di) {
    int yy = y - di;
    if (yy < 0 || (yy & 1) || (yy >> 1) >= NPATCH) continue;
    int i = yy >> 1;
    for (int dj = 0; dj < 3; ++dj) {
      int xc = xx - dj;
      if (xc < 0 || (xc & 1) || (xc >> 1) >= NPATCH) continue;
      int j = xc >> 1;
      int l = i * NPATCH + j;
      int m = wsi[OFF_IDX + ((size_t)b * L + l) * 4 + kk];
      int mi = m / NPATCH, mj = m % NPATCH;
      acc += rg[(2 * mi + di) * PSZ + 2 * mj + dj];
    }
  }
  out[(((size_t)b * 7 + 3 + kk) * PSZ + y) * PSZ + xx] = acc;
}

extern "C" void kernel_launch(void* const* d_in, const int* in_sizes, int n_in,
                              void* d_out, int out_size, void* d_ws, size_t ws_size,
                              hipStream_t stream) {
  const float* x = (const float*)d_in[0];
  const float* ref = (const float*)d_in[1];
  float* ws = (float*)d_ws;
  float* out = (float*)d_out;

  k12_gray<<<128, 256, 0, stream>>>(x, ref, ws, out);
  k4_mean<<<36, 1024, 0, stream>>>(ws);
  k5_norm<<<(2 * L + 255) / 256, 256, 0, stream>>>(ws);
  k6_topk<<<2 * NROWBLK * NS, TMAIN, 0, stream>>>(ws);
  k7_merge<<<(2 * L + 255) / 256, 256, 0, stream>>>(ws);
  k8_fold<<<(2 * KTOP * PSZ * PSZ + 255) / 256, 256, 0, stream>>>(ws, out);
}